// Round 10
// baseline (91.409 us; speedup 1.0000x reference)
//
#include <hip/hip_runtime.h>
#include <math.h>
#include <stdint.h>

#define HH 512
#define WW 512
#define BB 64
#define NP 13860
#define WPR 16                       // 32-bit words per image row
#define IMG_WORDS (BB * HH * WPR)    // 2 MB bit-image for all batches

struct GaussW { float g[9]; };

__device__ __forceinline__ int reflect_idx(int i) {
    if (i < 0) i = -i;
    if (i > 511) i = 1022 - i;
    return i;
}

// ----------------------------------------------------------------- zero ----
__global__ __launch_bounds__(256)
void zero_kernel(uint4* __restrict__ p) {
    p[blockIdx.x * 256 + threadIdx.x] = make_uint4(0u, 0u, 0u, 0u);
}

// ---------------------------------------------------------------- splat ----
// One thread = one (point, batch). Identical fp semantics to passing r4-r9.
__global__ __launch_bounds__(256)
void splat_kernel(const float* __restrict__ V,
                  const float* __restrict__ P,
                  const float* __restrict__ pts,
                  unsigned int* __restrict__ gbm) {
    __shared__ float VP[4][4];
    const int b = blockIdx.y;
    const int t = threadIdx.x;
    if (t < 16) {
        const int i = t >> 2, k = t & 3;
        const float* Pb = P + b * 16;
        const float* Vb = V + b * 16;
        float a = __fmul_rn(Pb[i*4+0], Vb[0*4+k]);
        a = __fmaf_rn(Pb[i*4+1], Vb[1*4+k], a);
        a = __fmaf_rn(Pb[i*4+2], Vb[2*4+k], a);
        a = __fmaf_rn(Pb[i*4+3], Vb[3*4+k], a);
        VP[i][k] = a;
    }
    __syncthreads();
    const int n = blockIdx.x * 256 + t;
    if (n >= NP) return;
    const float4 p = ((const float4*)pts)[n];
    float tp0, tp1, tp3;
    {
        float a = __fmul_rn(p.x, VP[0][0]);
        a = __fmaf_rn(p.y, VP[0][1], a);
        a = __fmaf_rn(p.z, VP[0][2], a);
        a = __fmaf_rn(p.w, VP[0][3], a);
        tp0 = a;
    }
    {
        float a = __fmul_rn(p.x, VP[1][0]);
        a = __fmaf_rn(p.y, VP[1][1], a);
        a = __fmaf_rn(p.z, VP[1][2], a);
        a = __fmaf_rn(p.w, VP[1][3], a);
        tp1 = a;
    }
    {
        float a = __fmul_rn(p.x, VP[3][0]);
        a = __fmaf_rn(p.y, VP[3][1], a);
        a = __fmaf_rn(p.z, VP[3][2], a);
        a = __fmaf_rn(p.w, VP[3][3], a);
        tp3 = a;
    }
    const float w = tp3;
    const float x = (w != 0.f) ? (tp0 / w) : tp0;
    const float y = (w != 0.f) ? (tp1 / w) : tp1;
    const float sxf = rintf(__fmul_rn(__fmul_rn(__fadd_rn(x, 1.f), 0.5f), 512.f));
    const float tmp = __fmul_rn(__fadd_rn(y, 1.f), 0.5f);
    const float syf = rintf(__fmul_rn(__fsub_rn(1.f, tmp), 512.f));
    int sx, sy;
    if (sxf >= 0.f && sxf < 512.f && syf >= 0.f && syf < 512.f) {
        sx = (int)sxf; sy = (int)syf;
    } else {
        sx = 511; sy = 511;   // JAX: flat=-1 wraps to last pixel, not dropped
    }
    atomicOr(&gbm[(b * HH + sy) * WPR + (sx >> 5)], 1u << (sx & 31));
}

// ------------------------------------------------ horizontal dilate (±4) ---
__global__ __launch_bounds__(256)
void hdil_kernel(const unsigned int* __restrict__ in,
                 unsigned int* __restrict__ out) {
    const int idx = blockIdx.x * 256 + threadIdx.x;
    const int wx = idx & (WPR - 1);
    const unsigned int w  = in[idx];
    const unsigned int wl = (wx > 0)       ? in[idx - 1] : 0u;
    const unsigned int wr = (wx < WPR - 1) ? in[idx + 1] : 0u;
    unsigned int hd = w;
#pragma unroll
    for (int k = 1; k <= 4; ++k) {
        hd |= (w << k) | (wl >> (32 - k));
        hd |= (w >> k) | (wr << (32 - k));
    }
    out[idx] = hd;
}

// -------------------------------------------------- vertical dilate (±4) ---
__global__ __launch_bounds__(256)
void vdil_kernel(const unsigned int* __restrict__ in,
                 unsigned int* __restrict__ out) {
    const int idx = blockIdx.x * 256 + threadIdx.x;
    const int b   = idx / (HH * WPR);
    const int rem = idx - b * (HH * WPR);
    const int r   = rem >> 4;          // row
    const int wx  = rem & (WPR - 1);
    const int lo = (r - 4 > 0) ? r - 4 : 0;
    const int hi = (r + 4 < HH - 1) ? r + 4 : HH - 1;
    const unsigned int* base = in + b * HH * WPR + wx;
    unsigned int acc = 0u;
    for (int rr = lo; rr <= hi; ++rr) acc |= base[rr * WPR];
    out[idx] = acc;
}

// ------------------- tile kernel: blur + threshold + store -----------------
// Barrier-free (one LUT barrier only): reads fully-dilated bitmap from
// global (L2-resident), uniform fast path, exact LUT path for mixed patches.
__global__ __launch_bounds__(256)
void tile_kernel(const unsigned int* __restrict__ gdil,
                 float* __restrict__ out, GaussW gw) {
    __shared__ float lut[512];

    const int b  = blockIdx.z;
    const int x0 = blockIdx.x * 64;
    const int y0 = blockIdx.y * 64;
    const int tx = threadIdx.x;          // 0..15 -> 4-col group
    const int ty = threadIdx.y;          // 0..15 -> 4-row group
    const int tid = ty * 16 + tx;

    // vertical-blur LUT over 9-bit column patterns (exact ascending-dy fma)
    for (int e = tid; e < 512; e += 256) {
        float acc = 0.f;
#pragma unroll
        for (int dy = 0; dy < 9; ++dy) {
            const float val = ((e >> dy) & 1) ? 255.f : 0.f;
            acc = __fmaf_rn(gw.g[dy], val, acc);
        }
        lut[e] = acc;
    }
    __syncthreads();

    const unsigned int* gb = gdil + b * HH * WPR;
    const int c0 = 4 * tx;

    // 12 row word-offsets (reflected)
    int rk[12];
    const int rbase = y0 + 4 * ty - 4;
#pragma unroll
    for (int k = 0; k < 12; ++k)
        rk[k] = reflect_idx(rbase + k) * WPR;

    const bool colRef = (x0 == 0 && tx == 0) || (x0 == 448 && tx == 15);

    // mode: 0 = all-zero, 1 = all-one, 2 = mixed (exact path)
    int mode = 2;
    unsigned int v12[12];

    if (!colRef) {
        const int colA = x0 + c0 - 4;            // >= 0 for non-reflected lanes
        const int wA = colA >> 5;
        const int w2 = (wA + 1 < WPR) ? wA + 1 : WPR - 1;
        const int sh = colA & 31;
        unsigned int e12[12], fOr = 0u, fAnd = 0xFFFu;
#pragma unroll
        for (int k = 0; k < 12; ++k) {
            const unsigned long long cat =
                (((unsigned long long)gb[rk[k] + w2]) << 32) |
                (unsigned long long)gb[rk[k] + wA];
            e12[k] = (unsigned int)(cat >> sh) & 0xFFFu;
            fOr |= e12[k]; fAnd &= e12[k];
        }
        // Fast paths are exact: all-zero window -> every tap 0 -> sum 0
        // (rintf(0)>100 false). All-one -> every vs = lut[511] ~ 255,
        // hblur ~ 255*(sum g) in [254.9,255.1] -> rintf > 100 true.
        if (fOr == 0u)           mode = 0;
        else if (fAnd == 0xFFFu) mode = 1;
        else {
            // transpose 12x12 bits: v12[j] bit k = e12[k] bit j
#pragma unroll
            for (int j = 0; j < 12; ++j) {
                unsigned int v = 0u;
#pragma unroll
                for (int k = 0; k < 12; ++k)
                    v |= ((e12[k] >> j) & 1u) << k;
                v12[j] = v;
            }
        }
    } else {
        // edge lanes: the 12 reflected cols all fold into one word
        const int wsel = (x0 == 0) ? 0 : WPR - 1;
        unsigned int d[12];
#pragma unroll
        for (int k = 0; k < 12; ++k) d[k] = gb[rk[k] + wsel];
#pragma unroll
        for (int j = 0; j < 12; ++j) {
            const int col = reflect_idx(x0 + c0 - 4 + j);
            const int shc = col & 31;
            unsigned int v = 0u;
#pragma unroll
            for (int k = 0; k < 12; ++k)
                v |= ((d[k] >> shc) & 1u) << k;
            v12[j] = v;
        }
    }

    // per output row: vertical LUT + horizontal 9-tap + threshold + store
#pragma unroll
    for (int r = 0; r < 4; ++r) {
        float4 mq;
        float* mp = (float*)&mq;
        if (mode == 0) {
            mq = make_float4(0.f, 0.f, 0.f, 0.f);
        } else if (mode == 1) {
            mq = make_float4(1.f, 1.f, 1.f, 1.f);
        } else {
            float f[12];
#pragma unroll
            for (int j = 0; j < 12; ++j)
                f[j] = lut[(v12[j] >> r) & 0x1FFu];
#pragma unroll
            for (int q = 0; q < 4; ++q) {
                float acc = 0.f;
#pragma unroll
                for (int dx = 0; dx < 9; ++dx)
                    acc = __fmaf_rn(gw.g[dx], f[q + dx], acc);
                mp[q] = (rintf(acc) > 100.f) ? 1.f : 0.f;
            }
        }
        const int yq = y0 + 4 * ty + r, xq = x0 + c0;
        float* o = out + ((size_t)(b * 3) * HH + yq) * WW + xq;
        *(float4*)(o)                       = mq;
        *(float4*)(o + (size_t)HH * WW)     = mq;
        *(float4*)(o + (size_t)2 * HH * WW) = mq;
    }
}

// ---------------------------------------------------------------- launch ---
extern "C" void kernel_launch(void* const* d_in, const int* in_sizes, int n_in,
                              void* d_out, int out_size, void* d_ws, size_t ws_size,
                              hipStream_t stream) {
    const float* V   = (const float*)d_in[0];
    const float* P   = (const float*)d_in[1];
    const float* pts = (const float*)d_in[2];
    float* out = (float*)d_out;
    unsigned int* buf0 = (unsigned int*)d_ws;     // raw bitmap -> final dilated
    unsigned int* buf1 = buf0 + IMG_WORDS;        // h-dilated intermediate

    // Gaussian weights, replicating numpy f64 computation incl. pairwise sum
    const double sigma = 0.3 * ((9 - 1) * 0.5 - 1.0) + 0.8;
    double gd[9];
    for (int i = 0; i < 9; ++i) {
        const double t = ((double)i - 4.0) / sigma;
        gd[i] = exp(-0.5 * (t * t));
    }
    double s = ((gd[0] + gd[1]) + (gd[2] + gd[3])) + ((gd[4] + gd[5]) + (gd[6] + gd[7]));
    s += gd[8];
    GaussW gw;
    for (int i = 0; i < 9; ++i) gw.g[i] = (float)(gd[i] / s);

    zero_kernel<<<IMG_WORDS / 4 / 256, 256, 0, stream>>>((uint4*)buf0);
    splat_kernel<<<dim3((NP + 255) / 256, BB), 256, 0, stream>>>(V, P, pts, buf0);
    hdil_kernel<<<IMG_WORDS / 256, 256, 0, stream>>>(buf0, buf1);
    vdil_kernel<<<IMG_WORDS / 256, 256, 0, stream>>>(buf1, buf0);
    tile_kernel<<<dim3(8, 8, BB), dim3(16, 16), 0, stream>>>(buf0, out, gw);
}

// Round 12
// 85.728 us; speedup vs baseline: 1.0663x; 1.0663x over previous
//
#include <hip/hip_runtime.h>
#include <math.h>
#include <stdint.h>

#define HH 512
#define WW 512
#define BB 64
#define NP 13860
#define WPR 16                       // 32-bit words per image row
#define IMG_WORDS (BB * HH * WPR)    // 2 MB bit-image for all batches
#define TW 256                       // tile width  (wave stores 1KB contiguous)
#define TH 16                        // tile height

typedef float vfloat4 __attribute__((ext_vector_type(4)));

struct GaussW { float g[9]; };

__device__ __forceinline__ int reflect_idx(int i) {
    if (i < 0) i = -i;
    if (i > 511) i = 1022 - i;
    return i;
}

// ----------------------------------------------------------------- zero ----
__global__ __launch_bounds__(256)
void zero_kernel(uint4* __restrict__ p) {
    p[blockIdx.x * 256 + threadIdx.x] = make_uint4(0u, 0u, 0u, 0u);
}

// ---------------------------------------------------------------- splat ----
// One thread = one (point, batch). Identical fp semantics to passing r4-r10.
__global__ __launch_bounds__(256)
void splat_kernel(const float* __restrict__ V,
                  const float* __restrict__ P,
                  const float* __restrict__ pts,
                  unsigned int* __restrict__ gbm) {
    __shared__ float VP[4][4];
    const int b = blockIdx.y;
    const int t = threadIdx.x;
    if (t < 16) {
        const int i = t >> 2, k = t & 3;
        const float* Pb = P + b * 16;
        const float* Vb = V + b * 16;
        float a = __fmul_rn(Pb[i*4+0], Vb[0*4+k]);
        a = __fmaf_rn(Pb[i*4+1], Vb[1*4+k], a);
        a = __fmaf_rn(Pb[i*4+2], Vb[2*4+k], a);
        a = __fmaf_rn(Pb[i*4+3], Vb[3*4+k], a);
        VP[i][k] = a;
    }
    __syncthreads();
    const int n = blockIdx.x * 256 + t;
    if (n >= NP) return;
    const float4 p = ((const float4*)pts)[n];
    float tp0, tp1, tp3;
    {
        float a = __fmul_rn(p.x, VP[0][0]);
        a = __fmaf_rn(p.y, VP[0][1], a);
        a = __fmaf_rn(p.z, VP[0][2], a);
        a = __fmaf_rn(p.w, VP[0][3], a);
        tp0 = a;
    }
    {
        float a = __fmul_rn(p.x, VP[1][0]);
        a = __fmaf_rn(p.y, VP[1][1], a);
        a = __fmaf_rn(p.z, VP[1][2], a);
        a = __fmaf_rn(p.w, VP[1][3], a);
        tp1 = a;
    }
    {
        float a = __fmul_rn(p.x, VP[3][0]);
        a = __fmaf_rn(p.y, VP[3][1], a);
        a = __fmaf_rn(p.z, VP[3][2], a);
        a = __fmaf_rn(p.w, VP[3][3], a);
        tp3 = a;
    }
    const float w = tp3;
    const float x = (w != 0.f) ? (tp0 / w) : tp0;
    const float y = (w != 0.f) ? (tp1 / w) : tp1;
    const float sxf = rintf(__fmul_rn(__fmul_rn(__fadd_rn(x, 1.f), 0.5f), 512.f));
    const float tmp = __fmul_rn(__fadd_rn(y, 1.f), 0.5f);
    const float syf = rintf(__fmul_rn(__fsub_rn(1.f, tmp), 512.f));
    int sx, sy;
    if (sxf >= 0.f && sxf < 512.f && syf >= 0.f && syf < 512.f) {
        sx = (int)sxf; sy = (int)syf;
    } else {
        sx = 511; sy = 511;   // JAX: flat=-1 wraps to last pixel, not dropped
    }
    atomicOr(&gbm[(b * HH + sy) * WPR + (sx >> 5)], 1u << (sx & 31));
}

// ------------------- tile kernel: dilate + blur + threshold + store --------
// 256x16 tile, dim3(64,4): each wave store = 1KB contiguous, nontemporal.
__global__ __launch_bounds__(256)
void tile_kernel(const unsigned int* __restrict__ gbm,
                 float* __restrict__ out, GaussW gw) {
    __shared__ unsigned int bm[32][10];  // raw bits: rows R0..R1, 10 halo words
    __shared__ unsigned int hd[32][10];  // horizontally dilated
    __shared__ unsigned int dl[24][10];  // fully dilated, rows RD0..RD1
    __shared__ float lut[512];           // vertical-blur LUT (exact fma chain)

    const int b   = blockIdx.z;
    const int x0  = blockIdx.x * TW;
    const int y0  = blockIdx.y * TH;
    const int lx  = threadIdx.x;         // 0..63 -> 4-col group within wave
    const int tyq = threadIdx.y;         // 0..3  -> 4-row group
    const int tid = tyq * 64 + lx;

    const int R0  = (y0 - 8 > 0) ? y0 - 8 : 0;
    const int R1  = (y0 + TH + 7 < 511) ? y0 + TH + 7 : 511;
    const int W0  = (x0 == 0) ? 0 : (x0 / 32 - 1);
    const int RD0 = (y0 - 4 > 0) ? y0 - 4 : 0;
    const int RD1 = (y0 + TH + 3 < 511) ? y0 + TH + 3 : 511;
    const int NR  = R1 - R0 + 1;         // <= 32

    // phase A: load bitmap halo + build LUT (exact ascending-dy fma chain)
    const unsigned int* gb = gbm + b * HH * WPR;
    for (int e = tid; e < 32 * 10; e += 256) {
        const int r = e / 10, j = e - r * 10;
        unsigned int v = 0u;
        if (r < NR && W0 + j < WPR) v = gb[(R0 + r) * WPR + (W0 + j)];
        bm[r][j] = v;
    }
    for (int e = tid; e < 512; e += 256) {
        float acc = 0.f;
#pragma unroll
        for (int dy = 0; dy < 9; ++dy) {
            const float val = ((e >> dy) & 1) ? 255.f : 0.f;
            acc = __fmaf_rn(gw.g[dy], val, acc);
        }
        lut[e] = acc;
    }
    __syncthreads();

    // phase B1: horizontal dilation (+-4). Missing outermost neighbor words
    // only corrupt halo-edge bits that are never read (same argument as r7).
    for (int e = tid; e < 32 * 10; e += 256) {
        const int r = e / 10, j = e - r * 10;
        const unsigned int w  = bm[r][j];
        const unsigned int wl = (j > 0) ? bm[r][j-1] : 0u;
        const unsigned int wr = (j < 9) ? bm[r][j+1] : 0u;
        unsigned int h = w;
#pragma unroll
        for (int k = 1; k <= 4; ++k) {
            h |= (w << k) | (wl >> (32 - k));
            h |= (w >> k) | (wr << (32 - k));
        }
        hd[r][j] = h;
    }
    __syncthreads();

    // phase B2: vertical dilation (+-4), clamped at image borders
    for (int e = tid; e < 24 * 10; e += 256) {
        const int r0 = e / 10, j = e - r0 * 10;
        const int r = RD0 + r0;
        unsigned int acc = 0u;
        if (r <= RD1) {
            const int lo = (r - 4 > 0) ? r - 4 : 0;
            const int hi = (r + 4 < 511) ? r + 4 : 511;
            for (int rr = lo; rr <= hi; ++rr) acc |= hd[rr - R0][j];
        }
        dl[r0][j] = acc;
    }
    __syncthreads();

    // phase C: 12 column-patterns for this thread's 4x4 patch
    const int c0 = 4 * lx;
    int rrk[12];
    const int rbase = y0 + 4 * tyq - 4;
#pragma unroll
    for (int k = 0; k < 12; ++k)
        rrk[k] = reflect_idx(rbase + k) - RD0;

    const bool colRef = (x0 == 0 && lx == 0) || (x0 + TW == WW && lx == 63);
    int mode = 2;                        // 0 all-zero, 1 all-one, 2 mixed
    unsigned int v12[12];

    if (!colRef) {
        const int colA = x0 + c0 - 4;    // >= 0 for non-reflected lanes
        const int wA = colA >> 5;
        const int jA = wA - W0;
        const int j2 = ((wA + 1 < WPR) ? wA + 1 : WPR - 1) - W0;
        const int sh = colA & 31;
        unsigned int e12[12], fOr = 0u, fAnd = 0xFFFu;
#pragma unroll
        for (int k = 0; k < 12; ++k) {
            const unsigned long long cat =
                (((unsigned long long)dl[rrk[k]][j2]) << 32) |
                (unsigned long long)dl[rrk[k]][jA];
            e12[k] = (unsigned int)(cat >> sh) & 0xFFFu;
            fOr |= e12[k]; fAnd &= e12[k];
        }
        // exact fast paths: all-zero -> blur 0 (not > 100); all-one ->
        // blur ~255 (>> 100); both decisions far from the threshold.
        if (fOr == 0u)           mode = 0;
        else if (fAnd == 0xFFFu) mode = 1;
        else {
#pragma unroll
            for (int j = 0; j < 12; ++j) {
                unsigned int v = 0u;
#pragma unroll
                for (int k = 0; k < 12; ++k)
                    v |= ((e12[k] >> j) & 1u) << k;
                v12[j] = v;
            }
        }
    } else {
        // reflected-column lanes: 12 cols fold into a single word
        const int jE = (x0 == 0) ? 0 : (WPR - 1 - W0);
        unsigned int d[12];
#pragma unroll
        for (int k = 0; k < 12; ++k) d[k] = dl[rrk[k]][jE];
#pragma unroll
        for (int j = 0; j < 12; ++j) {
            const int col = reflect_idx(x0 + c0 - 4 + j);
            const int shc = col & 31;
            unsigned int v = 0u;
#pragma unroll
            for (int k = 0; k < 12; ++k)
                v |= ((d[k] >> shc) & 1u) << k;
            v12[j] = v;
        }
    }

    // phase D: vertical LUT + horizontal 9-tap + threshold + nt stores.
    // Wave (tyq fixed) stores 64 lanes x float4 = 1KB contiguous per plane.
#pragma unroll
    for (int r = 0; r < 4; ++r) {
        vfloat4 mq;
        if (mode == 0) {
            mq = (vfloat4)(0.f);
        } else if (mode == 1) {
            mq = (vfloat4)(1.f);
        } else {
            float f[12];
#pragma unroll
            for (int j = 0; j < 12; ++j)
                f[j] = lut[(v12[j] >> r) & 0x1FFu];
#pragma unroll
            for (int q = 0; q < 4; ++q) {
                float acc = 0.f;
#pragma unroll
                for (int dx = 0; dx < 9; ++dx)
                    acc = __fmaf_rn(gw.g[dx], f[q + dx], acc);
                mq[q] = (rintf(acc) > 100.f) ? 1.f : 0.f;
            }
        }
        const int yq = y0 + 4 * tyq + r;
        float* o = out + ((size_t)(b * 3) * HH + yq) * WW + x0 + c0;
        __builtin_nontemporal_store(mq, (vfloat4*)(o));
        __builtin_nontemporal_store(mq, (vfloat4*)(o + (size_t)HH * WW));
        __builtin_nontemporal_store(mq, (vfloat4*)(o + (size_t)2 * HH * WW));
    }
}

// ---------------------------------------------------------------- launch ---
extern "C" void kernel_launch(void* const* d_in, const int* in_sizes, int n_in,
                              void* d_out, int out_size, void* d_ws, size_t ws_size,
                              hipStream_t stream) {
    const float* V   = (const float*)d_in[0];
    const float* P   = (const float*)d_in[1];
    const float* pts = (const float*)d_in[2];
    float* out = (float*)d_out;
    unsigned int* gbm = (unsigned int*)d_ws;   // 2 MB bit-image

    // Gaussian weights, replicating numpy f64 computation incl. pairwise sum
    const double sigma = 0.3 * ((9 - 1) * 0.5 - 1.0) + 0.8;
    double gd[9];
    for (int i = 0; i < 9; ++i) {
        const double t = ((double)i - 4.0) / sigma;
        gd[i] = exp(-0.5 * (t * t));
    }
    double s = ((gd[0] + gd[1]) + (gd[2] + gd[3])) + ((gd[4] + gd[5]) + (gd[6] + gd[7]));
    s += gd[8];
    GaussW gw;
    for (int i = 0; i < 9; ++i) gw.g[i] = (float)(gd[i] / s);

    zero_kernel<<<IMG_WORDS / 4 / 256, 256, 0, stream>>>((uint4*)gbm);
    splat_kernel<<<dim3((NP + 255) / 256, BB), 256, 0, stream>>>(V, P, pts, gbm);
    tile_kernel<<<dim3(WW / TW, HH / TH, BB), dim3(64, 4), 0, stream>>>(gbm, out, gw);
}